// Round 1
// baseline (448.779 us; speedup 1.0000x reference)
//
#include <hip/hip_runtime.h>

#define BETA 0.9f
#define THRESH 1.0f

constexpr int Bsz  = 64;
constexpr int Din  = 1024;
constexpr int Dout = 1024;
constexpr int KCH  = 4;            // split-K chunks
constexpr int KLEN = Din / KCH;    // 256
constexpr int NBJ  = Bsz * Dout;   // 65536 elements of [B, Dout]

// ---------------------------------------------------------------------------
// A1: split-K partial GEMM.  partial[p][b*Dout + j] = sum_{k in chunk p} x[b,k]*W[k,j]
// grid = KCH * Bsz * (Dout/256) = 1024 blocks of 256  -> 4096 waves (16/CU)
// x[b,k] is block-uniform -> scalar loads; W[k*Dout+j] coalesced across lanes.
// ---------------------------------------------------------------------------
__global__ __launch_bounds__(256) void gemm_partial(const float* __restrict__ x,
                                                    const float* __restrict__ W,
                                                    float* __restrict__ partial) {
    int blk = blockIdx.x;          // 0..1023
    int p   = blk >> 8;            // k-chunk 0..3
    int rem = blk & 255;
    int b   = rem >> 2;            // 0..63
    int jc  = rem & 3;             // 0..3
    int j   = (jc << 8) + threadIdx.x;

    const float* xr = x + b * Din + p * KLEN;
    const float* Wc = W + (size_t)(p * KLEN) * Dout + j;

    float acc = 0.f;
#pragma unroll 16
    for (int k = 0; k < KLEN; ++k) {
        acc = fmaf(xr[k], Wc[(size_t)k * Dout], acc);
    }
    partial[(size_t)p * NBJ + b * Dout + j] = acc;
}

// ---------------------------------------------------------------------------
// A2: reduce partials, LIF elementwise, E_b update, stash one_m for kernel B.
// ---------------------------------------------------------------------------
__global__ __launch_bounds__(256) void lif_elem(const float* __restrict__ partial,
                                                const float* __restrict__ bias,
                                                const float* __restrict__ u0,
                                                const float* __restrict__ E_b,
                                                float* __restrict__ out_spk,
                                                float* __restrict__ out_u,
                                                float* __restrict__ out_Eb,
                                                float* __restrict__ one_m_ws) {
    int idx = blockIdx.x * 256 + threadIdx.x;   // 0..65535
    int j   = idx & (Dout - 1);

    float I = partial[idx] + partial[NBJ + idx] + partial[2 * NBJ + idx]
            + partial[3 * NBJ + idx] + bias[j];
    float v    = fmaf(BETA, u0[idx], I);
    float vt   = v - THRESH;
    float spk  = vt > 0.f ? 1.f : 0.f;
    float a    = 1.f + fabsf(vt);
    float sg   = 1.f / (a * a);
    float u_nw = v - THRESH * spk;
    float om   = 1.f - THRESH * sg;            // one_m = d u_new / d v

    out_spk[idx]   = spk;
    out_u[idx]     = u_nw;
    // E_b_new = du_du*E_b + one_m, du_du = BETA*one_m  ->  one_m*(BETA*E_b + 1)
    out_Eb[idx]    = om * fmaf(BETA, E_b[idx], 1.f);
    one_m_ws[idx]  = om;
}

// ---------------------------------------------------------------------------
// B: the big stream.  E_W_new[b,i,j] = one_m[b,j] * (BETA*E_W[b,i,j] + x[b,i])
// float4 over j; one (b,i) row per 256-thread block slice. 512 MB HBM traffic.
// ---------------------------------------------------------------------------
__global__ __launch_bounds__(256) void ew_update(const float* __restrict__ E_W,
                                                 const float* __restrict__ x,
                                                 const float* __restrict__ one_m,
                                                 float* __restrict__ out_EW) {
    unsigned vidx = blockIdx.x * 256u + threadIdx.x;  // float4 index, < 16777216
    unsigned b    = vidx >> 18;            // Din*Dout/4 = 262144 vec4 per b
    unsigned rem  = vidx & 262143u;
    unsigned i    = rem >> 8;              // row within sample
    unsigned jv   = rem & 255u;            // vec4 column

    float        xs = x[b * Din + i];                       // block-uniform
    const float4 om = ((const float4*)one_m)[(b << 8) + jv];
    float4       e  = ((const float4*)E_W)[vidx];

    float4 r;
    r.x = om.x * fmaf(BETA, e.x, xs);
    r.y = om.y * fmaf(BETA, e.y, xs);
    r.z = om.z * fmaf(BETA, e.z, xs);
    r.w = om.w * fmaf(BETA, e.w, xs);
    ((float4*)out_EW)[vidx] = r;
}

extern "C" void kernel_launch(void* const* d_in, const int* in_sizes, int n_in,
                              void* d_out, int out_size, void* d_ws, size_t ws_size,
                              hipStream_t stream) {
    const float* x    = (const float*)d_in[0];
    const float* W    = (const float*)d_in[1];
    const float* bias = (const float*)d_in[2];
    const float* u0   = (const float*)d_in[3];
    const float* E_W  = (const float*)d_in[4];
    const float* E_b  = (const float*)d_in[5];

    float* out     = (float*)d_out;
    float* out_spk = out;                       // [64,1024]
    float* out_u   = out + NBJ;                 // [64,1024]
    float* out_EW  = out + 2 * NBJ;             // [64,1024,1024]
    float* out_Eb  = out + 2 * NBJ + (size_t)Bsz * Din * Dout;  // [64,1024]

    float* partial = (float*)d_ws;              // KCH * 65536 floats = 1 MB
    float* one_m   = partial + KCH * NBJ;       // 65536 floats = 256 KB

    gemm_partial<<<KCH * Bsz * (Dout / 256), 256, 0, stream>>>(x, W, partial);
    lif_elem<<<NBJ / 256, 256, 0, stream>>>(partial, bias, u0, E_b,
                                            out_spk, out_u, out_Eb, one_m);
    ew_update<<<(Bsz * Din * Dout / 4) / 256, 256, 0, stream>>>(E_W, x, one_m, out_EW);
}